// Round 12
// baseline (301.471 us; speedup 1.0000x reference)
//
#include <hip/hip_runtime.h>

typedef __attribute__((ext_vector_type(8))) short short8v;
typedef __attribute__((ext_vector_type(4))) short short4v;
typedef __attribute__((ext_vector_type(4))) float floatx4;
typedef __attribute__((ext_vector_type(4))) unsigned uint4v;
typedef __attribute__((ext_vector_type(2))) unsigned long long ulong2v;

namespace {
constexpr int Bn = 4, Tn = 2048, Dn = 1024, Hn = 16, HSn = 64;
}

__device__ __forceinline__ short f2bf(float f) {
  unsigned u = __builtin_bit_cast(unsigned, f);
  u += 0x7fffu + ((u >> 16) & 1u);           // round-to-nearest-even
  return (short)(u >> 16);
}

// packed f32x2 -> bf16x2 via v_cvt_pk_bf16_f32 (no builtin on gfx950)
__device__ __forceinline__ unsigned pkbf2(float lo, float hi) {
  unsigned r;
  asm("v_cvt_pk_bf16_f32 %0, %1, %2" : "=v"(r) : "v"(lo), "v"(hi));
  return r;
}

typedef const __attribute__((address_space(1))) unsigned int guint_t;
typedef __attribute__((address_space(3))) unsigned int luint_t;

__device__ __forceinline__ void gload16(const void* g, void* l) {
  __builtin_amdgcn_global_load_lds((guint_t*)g, (luint_t*)l, 16, 0, 0);
}

// swizzled LDS read of 8 contiguous bf16 at (row, k-element) for 128B rows
__device__ __forceinline__ short8v rd8(const char* base, int row, int kel) {
  return *(const short8v*)(base + row * 128 + ((kel * 2) ^ ((row & 7) << 4)));
}

// ---------------------------------------------------------------------------
// Merged prep: blockIdx.x < 48   -> Wq/Wk/Wv [H][D][HS] -> wt [proj*1024+h*64+e][d]
//              48 <= x < 64*16/..: flatten: x<1024 -> weight transpose; else x-1024 -> cvt
__global__ __launch_bounds__(256) void prep_k(const float* __restrict__ x,
                                              const float* __restrict__ Wq, const float* __restrict__ Wk,
                                              const float* __restrict__ Wv, const float* __restrict__ Wo,
                                              short* __restrict__ xb, short* __restrict__ wt,
                                              short* __restrict__ wot) {
  if (blockIdx.x >= 1024) {                   // x fp32 -> bf16 (4096 blocks)
    const size_t i = ((size_t)(blockIdx.x - 1024) * 256 + threadIdx.x) * 8;
    const float4 a = *(const float4*)(x + i);
    const float4 b = *(const float4*)(x + i + 4);
    short8v o;
    o[0] = f2bf(a.x); o[1] = f2bf(a.y); o[2] = f2bf(a.z); o[3] = f2bf(a.w);
    o[4] = f2bf(b.x); o[5] = f2bf(b.y); o[6] = f2bf(b.z); o[7] = f2bf(b.w);
    *(short8v*)(xb + i) = o;
    return;
  }
  __shared__ float T[64][65];
  const int bx = blockIdx.x & 63, by = blockIdx.x >> 6;   // 64 x 16
  const int t = threadIdx.x;
  const int rr = t >> 2, c0 = (t & 3) * 4;
  const float* src;
  short* dst;
  if (bx < 48) {
    const int p = bx >> 4, h = bx & 15;
    const float* W = p == 0 ? Wq : p == 1 ? Wk : Wv;
    src = W + (size_t)h * (Dn * HSn) + (size_t)(by * 64 + rr) * HSn;
    dst = wt + ((size_t)p * 1024 + h * 64 + rr) * 1024 + by * 64;
  } else {
    const int ktile = bx - 48;
    src = Wo + (size_t)(ktile * 64 + rr) * Dn + by * 64;
    dst = wot + (size_t)(by * 64 + rr) * 1024 + ktile * 64;
  }
  #pragma unroll
  for (int q = 0; q < 4; ++q) {
    const float4 v = *(const float4*)(src + c0 + q * 16);
    T[rr][c0 + q * 16 + 0] = v.x; T[rr][c0 + q * 16 + 1] = v.y;
    T[rr][c0 + q * 16 + 2] = v.z; T[rr][c0 + q * 16 + 3] = v.w;
  }
  __syncthreads();
  #pragma unroll
  for (int q = 0; q < 4; ++q) {
    const int dl = c0 + q * 16;
    short4v ov = {f2bf(T[dl + 0][rr]), f2bf(T[dl + 1][rr]),
                  f2bf(T[dl + 2][rr]), f2bf(T[dl + 3][rr])};
    *(short4v*)(dst + dl) = ov;
  }
}

// ---------------------------------------------------------------------------
// 128x128 tile MFMA mainloop, K=1024, BK=64, 256 threads / 4 waves.
__device__ __forceinline__ void gemm_mainloop(const char* gA, const char* gB, char* As, char* Bs,
                                              floatx4 acc[4][4]) {
  const int tid = threadIdx.x;
  const int wv = tid >> 6, ln = tid & 63;
  const int wr = wv >> 1, wc = wv & 1;
  const int lr = ln >> 3, lg = ln & 7;
  const int fr = ln & 15, kq = ln >> 4;
  for (int kt = 0; kt < 16; ++kt) {
    __syncthreads();
    #pragma unroll
    for (int c = 0; c < 4; ++c) {
      const int r = wv * 32 + c * 8 + lr;
      const int sw = (lg * 16) ^ ((r & 7) * 16);
      gload16(gA + (size_t)r * 2048 + kt * 128 + sw, As + (wv * 32 + c * 8) * 128);
      gload16(gB + (size_t)r * 2048 + kt * 128 + sw, Bs + (wv * 32 + c * 8) * 128);
    }
    __syncthreads();
    #pragma unroll
    for (int kb = 0; kb < 2; ++kb) {
      const int k0 = kb * 32 + kq * 8;
      short8v af[4], bfr[4];
      #pragma unroll
      for (int i = 0; i < 4; ++i) af[i] = rd8(As, wr * 64 + i * 16 + fr, k0);
      #pragma unroll
      for (int j = 0; j < 4; ++j) bfr[j] = rd8(Bs, wc * 64 + j * 16 + fr, k0);
      #pragma unroll
      for (int i = 0; i < 4; ++i)
        #pragma unroll
        for (int j = 0; j < 4; ++j)
          acc[i][j] = __builtin_amdgcn_mfma_f32_16x16x32_bf16(af[i], bfr[j], acc[i][j], 0, 0, 0);
    }
  }
}

// fused QKV: q pre-scaled by (1/8)*log2(e) so attention softmax runs in exp2 domain
__global__ __launch_bounds__(256) void gemm_qkv_k(const short* __restrict__ xb, const short* __restrict__ wt,
                                                  short* __restrict__ qb, short* __restrict__ kb,
                                                  short* __restrict__ vb) {
  __shared__ __align__(16) char S[32768];
  char* As = S;
  char* Bs = S + 16384;
  const int m0 = blockIdx.x * 128, n0 = blockIdx.y * 128;
  floatx4 acc[4][4];
  #pragma unroll
  for (int i = 0; i < 4; ++i)
    #pragma unroll
    for (int j = 0; j < 4; ++j) acc[i][j] = floatx4{0.f, 0.f, 0.f, 0.f};
  gemm_mainloop((const char*)xb + (size_t)m0 * 2048, (const char*)wt + (size_t)n0 * 2048, As, Bs, acc);

  const int tid = threadIdx.x, wv = tid >> 6, ln = tid & 63;
  const int wr = wv >> 1, wc = wv & 1;
  const int proj = n0 >> 10;
  const int b = m0 >> 11;
  const int rb_ = (ln >> 4) * 4, fc = ln & 15;
  if (proj < 2) {
    short* dst = proj == 0 ? qb : kb;
    const float sc = proj == 0 ? 0.18033688011112042f : 1.0f;  // 0.125*log2e
    #pragma unroll
    for (int i = 0; i < 4; ++i) {
      const int m = m0 + wr * 64 + i * 16 + rb_;
      #pragma unroll
      for (int j = 0; j < 4; ++j) {
        const int n = n0 + wc * 64 + j * 16 + fc;
        const int h = (n >> 6) & 15, e = n & 63;
        short* dp = dst + ((size_t)(b * 16 + h) * Tn + (m & 2047)) * 64 + e;
        #pragma unroll
        for (int r = 0; r < 4; ++r) dp[(size_t)r * 64] = f2bf(acc[i][j][r] * sc);
      }
    }
  } else {
    // V: stage C as [n][m] bf16 in LDS (swizzled rows), then coalesced [e][t] stores
    __syncthreads();                          // all waves done reading As/Bs
    #pragma unroll
    for (int i = 0; i < 4; ++i) {
      const int ml = wr * 64 + i * 16 + rb_;  // 4-aligned
      #pragma unroll
      for (int j = 0; j < 4; ++j) {
        const int nl = wc * 64 + j * 16 + fc;
        short4v ov = {f2bf(acc[i][j][0]), f2bf(acc[i][j][1]),
                      f2bf(acc[i][j][2]), f2bf(acc[i][j][3])};
        *(short4v*)(S + nl * 256 + ((ml * 2) ^ ((nl & 7) << 4))) = ov;
      }
    }
    __syncthreads();
    const int t00 = m0 & 2047;
    #pragma unroll
    for (int it = 0; it < 8; ++it) {
      const int nl = it * 16 + (tid >> 4);    // lanes 0-15 share a row
      const int mc = (tid & 15) * 8;          // 8-short chunk within the row
      const int n = n0 + nl;
      const int h2 = (n >> 6) & 15, e = n & 63;
      const uint4v vvv = *(const uint4v*)(S + nl * 256 + ((mc * 2) ^ ((nl & 7) << 4)));
      *(uint4v*)(vb + ((size_t)(b * 16 + h2) * 64 + e) * Tn + t00 + mc) = vvv;
    }
  }
}

// ---------------------------------------------------------------------------
// Transposed MFMA flash attention: grid (bh, T/128), 4 waves x 32 q-rows.
// (r7 structure: per-block single q-tile, dbuf K/V, P in registers)
__global__ __launch_bounds__(256, 5) void attn_k(const short* __restrict__ qg, const short* __restrict__ kg,
                                                 const short* __restrict__ vg, short* __restrict__ og) {
  __shared__ __align__(16) char Ks[16384];     // 2 x 64 kv-rows (double buffer)
  __shared__ __align__(16) char Vs[16384];     // 2 x 64 e-rows of V^T (double buffer)
  const int qt = gridDim.y - 1 - blockIdx.y;   // longest causal blocks dispatch first
  const int bh = blockIdx.x;
  const int tid = threadIdx.x, wv = tid >> 6, ln = tid & 63;
  const int lr = ln >> 3, lg = ln & 7;         // staging: row-in-8, 16B chunk
  const int fr = ln & 15, kq = ln >> 4;        // fragment: row/col, k-octet
  const char* qbase = (const char*)qg + (size_t)bh * Tn * 128;
  const char* kbase = (const char*)kg + (size_t)bh * Tn * 128;
  const char* vbase = (const char*)vg + (size_t)bh * Tn * 128;   // [e][t], 4096B rows

  // first K/V tile -> buffer 0
  #pragma unroll
  for (int c = 0; c < 2; ++c) {
    const int r = c * 32 + wv * 8 + lr;
    const int sw = (lg * 16) ^ ((r & 7) * 16);
    gload16(kbase + (size_t)r * 128 + sw, Ks + (c * 32 + wv * 8) * 128);
    gload16(vbase + (size_t)r * 4096 + sw, Vs + (c * 32 + wv * 8) * 128);
  }

  // Q B-fragments direct from global (16B contiguous per lane, read once)
  const char* qrow0 = qbase + (size_t)(qt * 128 + wv * 32) * 128;
  short8v qf[2][2];
  #pragma unroll
  for (int c = 0; c < 2; ++c)
    #pragma unroll
    for (int kb = 0; kb < 2; ++kb)
      qf[c][kb] = *(const short8v*)(qrow0 + (c * 16 + fr) * 128 + kb * 64 + kq * 16);

  short8v ones8;                               // bf16 1.0 x8 -> A-operand of the l-MFMA
  #pragma unroll
  for (int i = 0; i < 8; ++i) ones8[i] = (short)0x3F80;

  floatx4 ot[4][2];                            // O^T acc: [e-group][q-group]
  #pragma unroll
  for (int f = 0; f < 4; ++f) { ot[f][0] = floatx4{0.f,0.f,0.f,0.f}; ot[f][1] = floatx4{0.f,0.f,0.f,0.f}; }
  floatx4 lacc[2] = {floatx4{0.f,0.f,0.f,0.f}, floatx4{0.f,0.f,0.f,0.f}};
  float m_i[2] = {-1e30f, -1e30f};

  const int swz = (fr & 7) * 16;               // V^T/K row swizzle (row&7 == fr&7)
  const int nkt = 2 * qt + 2;
  const int q0w = qt * 128 + wv * 32;          // wave's first q-row
  __syncthreads();                             // first K/V tile ready

  for (int kt = 0; kt < nkt; ++kt) {
    const int cur = kt & 1;
    if (kt + 1 < nkt) {                        // prefetch next K/V tile into other buffer
      #pragma unroll
      for (int c = 0; c < 2; ++c) {
        const int r = c * 32 + wv * 8 + lr;
        const int sw = (lg * 16) ^ ((r & 7) * 16);
        gload16(kbase + (size_t)((kt + 1) * 64 + r) * 128 + sw,
                Ks + (cur ^ 1) * 8192 + (c * 32 + wv * 8) * 128);
        gload16(vbase + (size_t)r * 4096 + (size_t)(kt + 1) * 128 + sw,
                Vs + (cur ^ 1) * 8192 + (c * 32 + wv * 8) * 128);
      }
    }
    if (kt * 64 <= q0w + 31) {                 // skip fully-masked waves
      const char* Ksc = Ks + cur * 8192;
      const char* Vsc = Vs + cur * 8192;
      // S^T = K . Q  (C: row = kv, col = q)
      floatx4 st[2][4];
      #pragma unroll
      for (int f = 0; f < 4; ++f) { st[0][f] = floatx4{0.f,0.f,0.f,0.f}; st[1][f] = floatx4{0.f,0.f,0.f,0.f}; }
      #pragma unroll
      for (int kb = 0; kb < 2; ++kb) {
        const int e0 = kb * 32 + kq * 8;
        #pragma unroll
        for (int f = 0; f < 4; ++f) {
          const short8v kf = rd8(Ksc, f * 16 + fr, e0);
          st[0][f] = __builtin_amdgcn_mfma_f32_16x16x32_bf16(kf, qf[0][kb], st[0][f], 0, 0, 0);
          st[1][f] = __builtin_amdgcn_mfma_f32_16x16x32_bf16(kf, qf[1][kb], st[1][f], 0, 0, 0);
        }
      }
      if (kt * 64 + 63 > q0w) {                // causal mask (diag-overlapping tiles)
        #pragma unroll
        for (int c = 0; c < 2; ++c) {
          const int q = q0w + c * 16 + fr;
          #pragma unroll
          for (int f = 0; f < 4; ++f)
            #pragma unroll
            for (int r = 0; r < 4; ++r)
              if (kt * 64 + f * 16 + kq * 4 + r > q) st[c][f][r] = -3.0e38f;
        }
      }
      // tile max, then cross-lane over the 4 kv row-groups
      float mx[2];
      #pragma unroll
      for (int c = 0; c < 2; ++c) {
        float v = fmaxf(fmaxf(st[c][0][0], st[c][0][1]), st[c][0][2]);
        v = fmaxf(fmaxf(v, st[c][0][3]), st[c][1][0]);
        v = fmaxf(fmaxf(v, st[c][1][1]), st[c][1][2]);
        v = fmaxf(fmaxf(v, st[c][1][3]), st[c][2][0]);
        v = fmaxf(fmaxf(v, st[c][2][1]), st[c][2][2]);
        v = fmaxf(fmaxf(v, st[c][2][3]), st[c][3][0]);
        v = fmaxf(fmaxf(v, st[c][3][1]), st[c][3][2]);
        v = fmaxf(v, st[c][3][3]);
        v = fmaxf(v, __shfl_xor(v, 16, 64));
        v = fmaxf(v, __shfl_xor(v, 32, 64));
        mx[c] = v;
      }
      // defer-max (T13): rescale only when some lane's max grew by > 8 (log2 units)
      const bool noresc = __all((mx[0] <= m_i[0] + 8.f) && (mx[1] <= m_i[1] + 8.f));
      if (!noresc) {
        #pragma unroll
        for (int c = 0; c < 2; ++c) {
          const float mn = fmaxf(m_i[c], mx[c]);
          const float al = exp2f(m_i[c] - mn);
          m_i[c] = mn;
          lacc[c] *= al;
          #pragma unroll
          for (int f = 0; f < 4; ++f) ot[f][c] *= al;
        }
      }
      // P^T B-fragments in registers: slot (kb, j) <- exp2(st[c][kb + 2*(j>>2)][j&3] - m)
      short8v pbv[2][2];
      #pragma unroll
      for (int c = 0; c < 2; ++c)
        #pragma unroll
        for (int kb = 0; kb < 2; ++kb) {
          uint4v u;
          u[0] = pkbf2(exp2f(st[c][kb][0] - m_i[c]),     exp2f(st[c][kb][1] - m_i[c]));
          u[1] = pkbf2(exp2f(st[c][kb][2] - m_i[c]),     exp2f(st[c][kb][3] - m_i[c]));
          u[2] = pkbf2(exp2f(st[c][kb + 2][0] - m_i[c]), exp2f(st[c][kb + 2][1] - m_i[c]));
          u[3] = pkbf2(exp2f(st[c][kb + 2][2] - m_i[c]), exp2f(st[c][kb + 2][3] - m_i[c]));
          pbv[c][kb] = __builtin_bit_cast(short8v, u);
        }
      // l += ones . P^T  (row-sum over kv on the matrix pipe)
      #pragma unroll
      for (int kb = 0; kb < 2; ++kb) {
        lacc[0] = __builtin_amdgcn_mfma_f32_16x16x32_bf16(ones8, pbv[0][kb], lacc[0], 0, 0, 0);
        lacc[1] = __builtin_amdgcn_mfma_f32_16x16x32_bf16(ones8, pbv[1][kb], lacc[1], 0, 0, 0);
      }
      // O^T += V^T . P^T with the SAME permuted depth: A slots j=0..3 -> kv=kb*16+kq*4+j,
      // j=4..7 -> kv=kb*16+32+kq*4+(j-4): two 8B LDS reads per fragment.
      #pragma unroll
      for (int kb = 0; kb < 2; ++kb) {
        const int blo = (kb * 32 + kq * 8) ^ swz;
        const int bhi = (kb * 32 + 64 + kq * 8) ^ swz;
        #pragma unroll
        for (int f = 0; f < 4; ++f) {
          const char* vrow = Vsc + (f * 16 + fr) * 128;
          ulong2v vv;
          vv[0] = *(const unsigned long long*)(vrow + blo);
          vv[1] = *(const unsigned long long*)(vrow + bhi);
          const short8v vf = __builtin_bit_cast(short8v, vv);
          ot[f][0] = __builtin_amdgcn_mfma_f32_16x16x32_bf16(vf, pbv[0][kb], ot[f][0], 0, 0, 0);
          ot[f][1] = __builtin_amdgcn_mfma_f32_16x16x32_bf16(vf, pbv[1][kb], ot[f][1], 0, 0, 0);
        }
      }
    }
    __syncthreads();                           // drains prefetch; frees cur for overwrite
  }

  const int b = bh >> 4, h = bh & 15;
  #pragma unroll
  for (int c = 0; c < 2; ++c) {
    const float inv = 1.0f / lacc[c][0];
    const size_t t = (size_t)(b * Tn + qt * 128 + wv * 32 + c * 16 + fr);
    #pragma unroll
    for (int f = 0; f < 4; ++f) {
      uint2 o4 = {pkbf2(ot[f][c][0] * inv, ot[f][c][1] * inv),
                  pkbf2(ot[f][c][2] * inv, ot[f][c][3] * inv)};
      *(uint2*)(og + t * 1024 + h * 64 + f * 16 + kq * 4) = o4;
    }
  }
}

// ---------------------------------------------------------------------------
__global__ __launch_bounds__(256) void gemm_out_k(const short* __restrict__ ao, const short* __restrict__ wot,
                                                  const float* __restrict__ bo, float* __restrict__ out) {
  __shared__ __align__(16) char S[32768];
  char* As = S;
  char* Bs = S + 16384;
  const int m0 = blockIdx.x * 128, n0 = blockIdx.y * 128;
  floatx4 acc[4][4];
  #pragma unroll
  for (int i = 0; i < 4; ++i)
    #pragma unroll
    for (int j = 0; j < 4; ++j) acc[i][j] = floatx4{0.f, 0.f, 0.f, 0.f};
  gemm_mainloop((const char*)ao + (size_t)m0 * 2048, (const char*)wot + (size_t)n0 * 2048, As, Bs, acc);

  const int tid = threadIdx.x, wv = tid >> 6, ln = tid & 63;
  const int wr = wv >> 1, wc = wv & 1;
  const int rb_ = (ln >> 4) * 4, fc = ln & 15;
  #pragma unroll
  for (int i = 0; i < 4; ++i) {
    const int m = m0 + wr * 64 + i * 16 + rb_;
    #pragma unroll
    for (int j = 0; j < 4; ++j) {
      const int n = n0 + wc * 64 + j * 16 + fc;
      const float bias = bo[n];
      #pragma unroll
      for (int r = 0; r < 4; ++r) out[(size_t)(m + r) * Dn + n] = acc[i][j][r] + bias;
    }
  }
}

extern "C" void kernel_launch(void* const* d_in, const int* in_sizes, int n_in,
                              void* d_out, int out_size, void* d_ws, size_t ws_size,
                              hipStream_t stream) {
  const float* x  = (const float*)d_in[0];
  const float* Wq = (const float*)d_in[1];
  const float* Wk = (const float*)d_in[2];
  const float* Wv = (const float*)d_in[3];
  const float* Wo = (const float*)d_in[4];
  const float* bo = (const float*)d_in[5];
  float* out = (float*)d_out;

  char* ws = (char*)d_ws;
  short* xb  = (short*)(ws);                      // 16 MB  x bf16 [8192][1024]
  short* wt  = (short*)(ws + (16u << 20));        //  6 MB  Wqkv^T bf16 [3072][1024]
  short* wot = (short*)(ws + (22u << 20));        //  2 MB  Wo^T bf16 [1024][1024]
  short* qb  = (short*)(ws + (24u << 20));        // 16 MB  q bf16 [bh][t][e] (pre-scaled, log2e folded)
  short* kb  = (short*)(ws + (40u << 20));        // 16 MB  k bf16 [bh][t][e]
  short* vb  = (short*)(ws + (56u << 20));        // 16 MB  v^T bf16 [bh][e][t]
  short* ao  = (short*)(ws + (72u << 20));        // 16 MB  attn out bf16 [b][t][1024]

  prep_k<<<5120, 256, 0, stream>>>(x, Wq, Wk, Wv, Wo, xb, wt, wot);
  gemm_qkv_k<<<dim3(64, 24), 256, 0, stream>>>(xb, wt, qb, kb, vb);
  attn_k<<<dim3(64, 16), 256, 0, stream>>>(qb, kb, vb, ao);
  gemm_out_k<<<dim3(64, 8), 256, 0, stream>>>(ao, wot, bo, out);
}

// Round 13
// 168.674 us; speedup vs baseline: 1.7873x; 1.7873x over previous
//
#include <hip/hip_runtime.h>

typedef __attribute__((ext_vector_type(8))) short short8v;
typedef __attribute__((ext_vector_type(4))) short short4v;
typedef __attribute__((ext_vector_type(4))) float floatx4;
typedef __attribute__((ext_vector_type(4))) unsigned uint4v;
typedef __attribute__((ext_vector_type(2))) unsigned long long ulong2v;

namespace {
constexpr int Bn = 4, Tn = 2048, Dn = 1024, Hn = 16, HSn = 64;
}

__device__ __forceinline__ short f2bf(float f) {
  unsigned u = __builtin_bit_cast(unsigned, f);
  u += 0x7fffu + ((u >> 16) & 1u);           // round-to-nearest-even
  return (short)(u >> 16);
}

// packed f32x2 -> bf16x2 via v_cvt_pk_bf16_f32 (no builtin on gfx950)
__device__ __forceinline__ unsigned pkbf2(float lo, float hi) {
  unsigned r;
  asm("v_cvt_pk_bf16_f32 %0, %1, %2" : "=v"(r) : "v"(lo), "v"(hi));
  return r;
}

typedef const __attribute__((address_space(1))) unsigned int guint_t;
typedef __attribute__((address_space(3))) unsigned int luint_t;

__device__ __forceinline__ void gload16(const void* g, void* l) {
  __builtin_amdgcn_global_load_lds((guint_t*)g, (luint_t*)l, 16, 0, 0);
}

// swizzled LDS read of 8 contiguous bf16 at (row, k-element) for 128B rows
__device__ __forceinline__ short8v rd8(const char* base, int row, int kel) {
  return *(const short8v*)(base + row * 128 + ((kel * 2) ^ ((row & 7) << 4)));
}

// ---------------------------------------------------------------------------
// Merged prep: blockIdx.x >= 1024 -> x cvt; else 64x16 weight-transpose tiles
__global__ __launch_bounds__(256) void prep_k(const float* __restrict__ x,
                                              const float* __restrict__ Wq, const float* __restrict__ Wk,
                                              const float* __restrict__ Wv, const float* __restrict__ Wo,
                                              short* __restrict__ xb, short* __restrict__ wt,
                                              short* __restrict__ wot) {
  if (blockIdx.x >= 1024) {                   // x fp32 -> bf16 (4096 blocks)
    const size_t i = ((size_t)(blockIdx.x - 1024) * 256 + threadIdx.x) * 8;
    const float4 a = *(const float4*)(x + i);
    const float4 b = *(const float4*)(x + i + 4);
    short8v o;
    o[0] = f2bf(a.x); o[1] = f2bf(a.y); o[2] = f2bf(a.z); o[3] = f2bf(a.w);
    o[4] = f2bf(b.x); o[5] = f2bf(b.y); o[6] = f2bf(b.z); o[7] = f2bf(b.w);
    *(short8v*)(xb + i) = o;
    return;
  }
  __shared__ float T[64][65];
  const int bx = blockIdx.x & 63, by = blockIdx.x >> 6;   // 64 x 16
  const int t = threadIdx.x;
  const int rr = t >> 2, c0 = (t & 3) * 4;
  const float* src;
  short* dst;
  if (bx < 48) {
    const int p = bx >> 4, h = bx & 15;
    const float* W = p == 0 ? Wq : p == 1 ? Wk : Wv;
    src = W + (size_t)h * (Dn * HSn) + (size_t)(by * 64 + rr) * HSn;
    dst = wt + ((size_t)p * 1024 + h * 64 + rr) * 1024 + by * 64;
  } else {
    const int ktile = bx - 48;
    src = Wo + (size_t)(ktile * 64 + rr) * Dn + by * 64;
    dst = wot + (size_t)(by * 64 + rr) * 1024 + ktile * 64;
  }
  #pragma unroll
  for (int q = 0; q < 4; ++q) {
    const float4 v = *(const float4*)(src + c0 + q * 16);
    T[rr][c0 + q * 16 + 0] = v.x; T[rr][c0 + q * 16 + 1] = v.y;
    T[rr][c0 + q * 16 + 2] = v.z; T[rr][c0 + q * 16 + 3] = v.w;
  }
  __syncthreads();
  #pragma unroll
  for (int q = 0; q < 4; ++q) {
    const int dl = c0 + q * 16;
    short4v ov = {f2bf(T[dl + 0][rr]), f2bf(T[dl + 1][rr]),
                  f2bf(T[dl + 2][rr]), f2bf(T[dl + 3][rr])};
    *(short4v*)(dst + dl) = ov;
  }
}

// ---------------------------------------------------------------------------
// 128x128 tile MFMA mainloop, K=1024, BK=64, 256 threads / 4 waves.
__device__ __forceinline__ void gemm_mainloop(const char* gA, const char* gB, char* As, char* Bs,
                                              floatx4 acc[4][4]) {
  const int tid = threadIdx.x;
  const int wv = tid >> 6, ln = tid & 63;
  const int wr = wv >> 1, wc = wv & 1;
  const int lr = ln >> 3, lg = ln & 7;
  const int fr = ln & 15, kq = ln >> 4;
  for (int kt = 0; kt < 16; ++kt) {
    __syncthreads();
    #pragma unroll
    for (int c = 0; c < 4; ++c) {
      const int r = wv * 32 + c * 8 + lr;
      const int sw = (lg * 16) ^ ((r & 7) * 16);
      gload16(gA + (size_t)r * 2048 + kt * 128 + sw, As + (wv * 32 + c * 8) * 128);
      gload16(gB + (size_t)r * 2048 + kt * 128 + sw, Bs + (wv * 32 + c * 8) * 128);
    }
    __syncthreads();
    #pragma unroll
    for (int kb = 0; kb < 2; ++kb) {
      const int k0 = kb * 32 + kq * 8;
      short8v af[4], bfr[4];
      #pragma unroll
      for (int i = 0; i < 4; ++i) af[i] = rd8(As, wr * 64 + i * 16 + fr, k0);
      #pragma unroll
      for (int j = 0; j < 4; ++j) bfr[j] = rd8(Bs, wc * 64 + j * 16 + fr, k0);
      #pragma unroll
      for (int i = 0; i < 4; ++i)
        #pragma unroll
        for (int j = 0; j < 4; ++j)
          acc[i][j] = __builtin_amdgcn_mfma_f32_16x16x32_bf16(af[i], bfr[j], acc[i][j], 0, 0, 0);
    }
  }
}

// fused QKV: q pre-scaled by (1/8)*log2(e) so attention softmax runs in exp2 domain
__global__ __launch_bounds__(256) void gemm_qkv_k(const short* __restrict__ xb, const short* __restrict__ wt,
                                                  short* __restrict__ qb, short* __restrict__ kb,
                                                  short* __restrict__ vb) {
  __shared__ __align__(16) char S[32768];
  char* As = S;
  char* Bs = S + 16384;
  const int m0 = blockIdx.x * 128, n0 = blockIdx.y * 128;
  floatx4 acc[4][4];
  #pragma unroll
  for (int i = 0; i < 4; ++i)
    #pragma unroll
    for (int j = 0; j < 4; ++j) acc[i][j] = floatx4{0.f, 0.f, 0.f, 0.f};
  gemm_mainloop((const char*)xb + (size_t)m0 * 2048, (const char*)wt + (size_t)n0 * 2048, As, Bs, acc);

  const int tid = threadIdx.x, wv = tid >> 6, ln = tid & 63;
  const int wr = wv >> 1, wc = wv & 1;
  const int proj = n0 >> 10;
  const int b = m0 >> 11;
  const int rb_ = (ln >> 4) * 4, fc = ln & 15;
  if (proj < 2) {
    short* dst = proj == 0 ? qb : kb;
    const float sc = proj == 0 ? 0.18033688011112042f : 1.0f;  // 0.125*log2e
    #pragma unroll
    for (int i = 0; i < 4; ++i) {
      const int m = m0 + wr * 64 + i * 16 + rb_;
      #pragma unroll
      for (int j = 0; j < 4; ++j) {
        const int n = n0 + wc * 64 + j * 16 + fc;
        const int h = (n >> 6) & 15, e = n & 63;
        short* dp = dst + ((size_t)(b * 16 + h) * Tn + (m & 2047)) * 64 + e;
        #pragma unroll
        for (int r = 0; r < 4; ++r) dp[(size_t)r * 64] = f2bf(acc[i][j][r] * sc);
      }
    }
  } else {
    // V: stage C as [n][m] bf16 in LDS (swizzled rows), then coalesced [e][t] stores
    __syncthreads();                          // all waves done reading As/Bs
    #pragma unroll
    for (int i = 0; i < 4; ++i) {
      const int ml = wr * 64 + i * 16 + rb_;  // 4-aligned
      #pragma unroll
      for (int j = 0; j < 4; ++j) {
        const int nl = wc * 64 + j * 16 + fc;
        short4v ov = {f2bf(acc[i][j][0]), f2bf(acc[i][j][1]),
                      f2bf(acc[i][j][2]), f2bf(acc[i][j][3])};
        *(short4v*)(S + nl * 256 + ((ml * 2) ^ ((nl & 7) << 4))) = ov;
      }
    }
    __syncthreads();
    const int t00 = m0 & 2047;
    #pragma unroll
    for (int it = 0; it < 8; ++it) {
      const int nl = it * 16 + (tid >> 4);    // lanes 0-15 share a row
      const int mc = (tid & 15) * 8;          // 8-short chunk within the row
      const int n = n0 + nl;
      const int h2 = (n >> 6) & 15, e = n & 63;
      const uint4v vvv = *(const uint4v*)(S + nl * 256 + ((mc * 2) ^ ((nl & 7) << 4)));
      *(uint4v*)(vb + ((size_t)(b * 16 + h2) * 64 + e) * Tn + t00 + mc) = vvv;
    }
  }
}

// ---------------------------------------------------------------------------
// Transposed MFMA flash attention: grid (bh, T/128), 4 waves x 32 q-rows.
// (r7 structure: per-block single q-tile, dbuf K/V, P in registers)
__global__ __launch_bounds__(256, 4) void attn_k(const short* __restrict__ qg, const short* __restrict__ kg,
                                                 const short* __restrict__ vg, short* __restrict__ og) {
  __shared__ __align__(16) char Ks[16384];     // 2 x 64 kv-rows (double buffer)
  __shared__ __align__(16) char Vs[16384];     // 2 x 64 e-rows of V^T (double buffer)
  const int qt = gridDim.y - 1 - blockIdx.y;   // longest causal blocks dispatch first
  const int bh = blockIdx.x;
  const int tid = threadIdx.x, wv = tid >> 6, ln = tid & 63;
  const int lr = ln >> 3, lg = ln & 7;         // staging: row-in-8, 16B chunk
  const int fr = ln & 15, kq = ln >> 4;        // fragment: row/col, k-octet
  const char* qbase = (const char*)qg + (size_t)bh * Tn * 128;
  const char* kbase = (const char*)kg + (size_t)bh * Tn * 128;
  const char* vbase = (const char*)vg + (size_t)bh * Tn * 128;   // [e][t], 4096B rows

  // first K/V tile -> buffer 0
  #pragma unroll
  for (int c = 0; c < 2; ++c) {
    const int r = c * 32 + wv * 8 + lr;
    const int sw = (lg * 16) ^ ((r & 7) * 16);
    gload16(kbase + (size_t)r * 128 + sw, Ks + (c * 32 + wv * 8) * 128);
    gload16(vbase + (size_t)r * 4096 + sw, Vs + (c * 32 + wv * 8) * 128);
  }

  // Q B-fragments direct from global (16B contiguous per lane, read once)
  const char* qrow0 = qbase + (size_t)(qt * 128 + wv * 32) * 128;
  short8v qf[2][2];
  #pragma unroll
  for (int c = 0; c < 2; ++c)
    #pragma unroll
    for (int kb = 0; kb < 2; ++kb)
      qf[c][kb] = *(const short8v*)(qrow0 + (c * 16 + fr) * 128 + kb * 64 + kq * 16);

  short8v ones8;                               // bf16 1.0 x8 -> A-operand of the l-MFMA
  #pragma unroll
  for (int i = 0; i < 8; ++i) ones8[i] = (short)0x3F80;

  floatx4 ot[4][2];                            // O^T acc: [e-group][q-group]
  #pragma unroll
  for (int f = 0; f < 4; ++f) { ot[f][0] = floatx4{0.f,0.f,0.f,0.f}; ot[f][1] = floatx4{0.f,0.f,0.f,0.f}; }
  floatx4 lacc[2] = {floatx4{0.f,0.f,0.f,0.f}, floatx4{0.f,0.f,0.f,0.f}};
  float m_i[2] = {-1e30f, -1e30f};

  const int swz = (fr & 7) * 16;               // V^T/K row swizzle (row&7 == fr&7)
  const int nkt = 2 * qt + 2;
  const int q0w = qt * 128 + wv * 32;          // wave's first q-row
  __syncthreads();                             // first K/V tile ready

  for (int kt = 0; kt < nkt; ++kt) {
    const int cur = kt & 1;
    if (kt + 1 < nkt) {                        // prefetch next K/V tile into other buffer
      #pragma unroll
      for (int c = 0; c < 2; ++c) {
        const int r = c * 32 + wv * 8 + lr;
        const int sw = (lg * 16) ^ ((r & 7) * 16);
        gload16(kbase + (size_t)((kt + 1) * 64 + r) * 128 + sw,
                Ks + (cur ^ 1) * 8192 + (c * 32 + wv * 8) * 128);
        gload16(vbase + (size_t)r * 4096 + (size_t)(kt + 1) * 128 + sw,
                Vs + (cur ^ 1) * 8192 + (c * 32 + wv * 8) * 128);
      }
    }
    if (kt * 64 <= q0w + 31) {                 // skip fully-masked waves
      const char* Ksc = Ks + cur * 8192;
      const char* Vsc = Vs + cur * 8192;
      // S^T = K . Q  (C: row = kv, col = q)
      floatx4 st[2][4];
      #pragma unroll
      for (int f = 0; f < 4; ++f) { st[0][f] = floatx4{0.f,0.f,0.f,0.f}; st[1][f] = floatx4{0.f,0.f,0.f,0.f}; }
      #pragma unroll
      for (int kb = 0; kb < 2; ++kb) {
        const int e0 = kb * 32 + kq * 8;
        #pragma unroll
        for (int f = 0; f < 4; ++f) {
          const short8v kf = rd8(Ksc, f * 16 + fr, e0);
          st[0][f] = __builtin_amdgcn_mfma_f32_16x16x32_bf16(kf, qf[0][kb], st[0][f], 0, 0, 0);
          st[1][f] = __builtin_amdgcn_mfma_f32_16x16x32_bf16(kf, qf[1][kb], st[1][f], 0, 0, 0);
        }
      }
      if (kt * 64 + 63 > q0w) {                // causal mask (diag-overlapping tiles)
        #pragma unroll
        for (int c = 0; c < 2; ++c) {
          const int q = q0w + c * 16 + fr;
          #pragma unroll
          for (int f = 0; f < 4; ++f)
            #pragma unroll
            for (int r = 0; r < 4; ++r)
              if (kt * 64 + f * 16 + kq * 4 + r > q) st[c][f][r] = -3.0e38f;
        }
      }
      // tile max, then cross-lane over the 4 kv row-groups
      float mx[2];
      #pragma unroll
      for (int c = 0; c < 2; ++c) {
        float v = fmaxf(fmaxf(st[c][0][0], st[c][0][1]), st[c][0][2]);
        v = fmaxf(fmaxf(v, st[c][0][3]), st[c][1][0]);
        v = fmaxf(fmaxf(v, st[c][1][1]), st[c][1][2]);
        v = fmaxf(fmaxf(v, st[c][1][3]), st[c][2][0]);
        v = fmaxf(fmaxf(v, st[c][2][1]), st[c][2][2]);
        v = fmaxf(fmaxf(v, st[c][2][3]), st[c][3][0]);
        v = fmaxf(fmaxf(v, st[c][3][1]), st[c][3][2]);
        v = fmaxf(v, st[c][3][3]);
        v = fmaxf(v, __shfl_xor(v, 16, 64));
        v = fmaxf(v, __shfl_xor(v, 32, 64));
        mx[c] = v;
      }
      // defer-max (T13): rescale only when some lane's max grew by > 8 (log2 units)
      const bool noresc = __all((mx[0] <= m_i[0] + 8.f) && (mx[1] <= m_i[1] + 8.f));
      if (!noresc) {
        #pragma unroll
        for (int c = 0; c < 2; ++c) {
          const float mn = fmaxf(m_i[c], mx[c]);
          const float al = exp2f(m_i[c] - mn);
          m_i[c] = mn;
          lacc[c] *= al;
          #pragma unroll
          for (int f = 0; f < 4; ++f) ot[f][c] *= al;
        }
      }
      // P^T B-fragments in registers: slot (kb, j) <- exp2(st[c][kb + 2*(j>>2)][j&3] - m)
      short8v pbv[2][2];
      #pragma unroll
      for (int c = 0; c < 2; ++c)
        #pragma unroll
        for (int kb = 0; kb < 2; ++kb) {
          uint4v u;
          u[0] = pkbf2(exp2f(st[c][kb][0] - m_i[c]),     exp2f(st[c][kb][1] - m_i[c]));
          u[1] = pkbf2(exp2f(st[c][kb][2] - m_i[c]),     exp2f(st[c][kb][3] - m_i[c]));
          u[2] = pkbf2(exp2f(st[c][kb + 2][0] - m_i[c]), exp2f(st[c][kb + 2][1] - m_i[c]));
          u[3] = pkbf2(exp2f(st[c][kb + 2][2] - m_i[c]), exp2f(st[c][kb + 2][3] - m_i[c]));
          pbv[c][kb] = __builtin_bit_cast(short8v, u);
        }
      // l += ones . P^T  (row-sum over kv on the matrix pipe)
      #pragma unroll
      for (int kb = 0; kb < 2; ++kb) {
        lacc[0] = __builtin_amdgcn_mfma_f32_16x16x32_bf16(ones8, pbv[0][kb], lacc[0], 0, 0, 0);
        lacc[1] = __builtin_amdgcn_mfma_f32_16x16x32_bf16(ones8, pbv[1][kb], lacc[1], 0, 0, 0);
      }
      // O^T += V^T . P^T with the SAME permuted depth: A slots j=0..3 -> kv=kb*16+kq*4+j,
      // j=4..7 -> kv=kb*16+32+kq*4+(j-4): two 8B LDS reads per fragment.
      #pragma unroll
      for (int kb = 0; kb < 2; ++kb) {
        const int blo = (kb * 32 + kq * 8) ^ swz;
        const int bhi = (kb * 32 + 64 + kq * 8) ^ swz;
        #pragma unroll
        for (int f = 0; f < 4; ++f) {
          const char* vrow = Vsc + (f * 16 + fr) * 128;
          ulong2v vv;
          vv[0] = *(const unsigned long long*)(vrow + blo);
          vv[1] = *(const unsigned long long*)(vrow + bhi);
          const short8v vf = __builtin_bit_cast(short8v, vv);
          ot[f][0] = __builtin_amdgcn_mfma_f32_16x16x32_bf16(vf, pbv[0][kb], ot[f][0], 0, 0, 0);
          ot[f][1] = __builtin_amdgcn_mfma_f32_16x16x32_bf16(vf, pbv[1][kb], ot[f][1], 0, 0, 0);
        }
      }
    }
    __syncthreads();                           // drains prefetch; frees cur for overwrite
  }

  const int b = bh >> 4, h = bh & 15;
  #pragma unroll
  for (int c = 0; c < 2; ++c) {
    const float inv = 1.0f / lacc[c][0];
    const size_t t = (size_t)(b * Tn + qt * 128 + wv * 32 + c * 16 + fr);
    #pragma unroll
    for (int f = 0; f < 4; ++f) {
      uint2 o4 = {pkbf2(ot[f][c][0] * inv, ot[f][c][1] * inv),
                  pkbf2(ot[f][c][2] * inv, ot[f][c][3] * inv)};
      *(uint2*)(og + t * 1024 + h * 64 + f * 16 + kq * 4) = o4;
    }
  }
}

// ---------------------------------------------------------------------------
__global__ __launch_bounds__(256) void gemm_out_k(const short* __restrict__ ao, const short* __restrict__ wot,
                                                  const float* __restrict__ bo, float* __restrict__ out) {
  __shared__ __align__(16) char S[32768];
  char* As = S;
  char* Bs = S + 16384;
  const int m0 = blockIdx.x * 128, n0 = blockIdx.y * 128;
  floatx4 acc[4][4];
  #pragma unroll
  for (int i = 0; i < 4; ++i)
    #pragma unroll
    for (int j = 0; j < 4; ++j) acc[i][j] = floatx4{0.f, 0.f, 0.f, 0.f};
  gemm_mainloop((const char*)ao + (size_t)m0 * 2048, (const char*)wot + (size_t)n0 * 2048, As, Bs, acc);

  const int tid = threadIdx.x, wv = tid >> 6, ln = tid & 63;
  const int wr = wv >> 1, wc = wv & 1;
  const int rb_ = (ln >> 4) * 4, fc = ln & 15;
  #pragma unroll
  for (int i = 0; i < 4; ++i) {
    const int m = m0 + wr * 64 + i * 16 + rb_;
    #pragma unroll
    for (int j = 0; j < 4; ++j) {
      const int n = n0 + wc * 64 + j * 16 + fc;
      const float bias = bo[n];
      #pragma unroll
      for (int r = 0; r < 4; ++r) out[(size_t)(m + r) * Dn + n] = acc[i][j][r] + bias;
    }
  }
}

extern "C" void kernel_launch(void* const* d_in, const int* in_sizes, int n_in,
                              void* d_out, int out_size, void* d_ws, size_t ws_size,
                              hipStream_t stream) {
  const float* x  = (const float*)d_in[0];
  const float* Wq = (const float*)d_in[1];
  const float* Wk = (const float*)d_in[2];
  const float* Wv = (const float*)d_in[3];
  const float* Wo = (const float*)d_in[4];
  const float* bo = (const float*)d_in[5];
  float* out = (float*)d_out;

  char* ws = (char*)d_ws;
  short* xb  = (short*)(ws);                      // 16 MB  x bf16 [8192][1024]
  short* wt  = (short*)(ws + (16u << 20));        //  6 MB  Wqkv^T bf16 [3072][1024]
  short* wot = (short*)(ws + (22u << 20));        //  2 MB  Wo^T bf16 [1024][1024]
  short* qb  = (short*)(ws + (24u << 20));        // 16 MB  q bf16 [bh][t][e] (pre-scaled, log2e folded)
  short* kb  = (short*)(ws + (40u << 20));        // 16 MB  k bf16 [bh][t][e]
  short* vb  = (short*)(ws + (56u << 20));        // 16 MB  v^T bf16 [bh][e][t]
  short* ao  = (short*)(ws + (72u << 20));        // 16 MB  attn out bf16 [b][t][1024]

  prep_k<<<5120, 256, 0, stream>>>(x, Wq, Wk, Wv, Wo, xb, wt, wot);
  gemm_qkv_k<<<dim3(64, 24), 256, 0, stream>>>(xb, wt, qb, kb, vb);
  attn_k<<<dim3(64, 16), 256, 0, stream>>>(qb, kb, vb, ao);
  gemm_out_k<<<dim3(64, 8), 256, 0, stream>>>(ao, wot, bo, out);
}